// Round 2
// baseline (28.912 us; speedup 1.0000x reference)
//
#include <hip/hip_runtime.h>
#include <math.h>

#define HDIM 128
#define SENT -1e30f

// Wave-parallel lower_bound: smallest idx with seg[idx] >= target, in [0, N].
// Must be called by all 64 lanes of a wave with uniform (N, target).
__device__ __forceinline__ int wave_lower_bound(const int* __restrict__ seg, int N, int target) {
    const int lane = threadIdx.x & 63;
    int lo = 0, hi = N;                       // answer in [lo, hi]
    while (hi - lo > 64) {
        int len = hi - lo;
        int chunk = (len + 63) >> 6;          // >= 2
        int pos = lo + lane * chunk;          // lane 0 probes lo
        int v = (pos < hi) ? seg[pos] : 0x7fffffff;
        unsigned long long bal = __ballot(v < target);
        int cnt = __popcll(bal);              // sorted -> lanes 0..cnt-1 true
        if (cnt == 0) { hi = lo; break; }     // seg[lo] >= target -> answer == lo
        int nlo = lo + (cnt - 1) * chunk + 1; // seg at (cnt-1)*chunk < target
        int nhi = (cnt < 64) ? min(hi, lo + cnt * chunk) : hi;
        lo = nlo; hi = nhi;
    }
    int pos = lo + lane;
    int v = (pos < hi) ? seg[pos] : 0x7fffffff;
    unsigned long long bal = __ballot(v < target);
    return lo + __popcll(bal);
}

__global__ void __launch_bounds__(1024)
att_pool_kernel(const float* __restrict__ s,      // [B,H]
                const float* __restrict__ x,      // [N,H] node_embeds
                const float* __restrict__ W,      // [H,H]
                const int*   __restrict__ seg,    // [N] sorted
                float*       __restrict__ out,    // [B,H]
                int N, int B)
{
    const int b    = blockIdx.x;
    const int tid  = threadIdx.x;
    const int wave = tid >> 6;        // 0..15
    const int lane = tid & 63;
    const int half = lane >> 5;       // 0 or 1
    const int hl   = lane & 31;       // lane within half: owns channels 4*hl..4*hl+3

    __shared__ float ws_lds[HDIM];
    __shared__ int   se[2];
    __shared__ float lm[32], ll[32];
    __shared__ float lacc[32][HDIM];
    __shared__ float sscale[32];
    __shared__ float sdenom;

    // ---- Phase 1: ws_b = W @ s_b  (ws[k] = sum_j W[k,j] * s[b,j]) ----
    {
        const int kloc = lane >> 3;           // 0..7
        const int g    = lane & 7;            // 0..7
        const int k    = wave * 8 + kloc;     // 0..127
        const float* Wr = W + (size_t)k * HDIM;
        const float* sr = s + (size_t)b * HDIM;
        float partial = 0.f;
        #pragma unroll
        for (int ii = 0; ii < 4; ++ii) {
            int j0 = (g + 8 * ii) * 4;        // lanes cover 32 float4 chunks
            float4 wv4 = *reinterpret_cast<const float4*>(Wr + j0);
            float4 sv4 = *reinterpret_cast<const float4*>(sr + j0);
            partial += wv4.x * sv4.x + wv4.y * sv4.y + wv4.z * sv4.z + wv4.w * sv4.w;
        }
        partial += __shfl_xor(partial, 1, 64);
        partial += __shfl_xor(partial, 2, 64);
        partial += __shfl_xor(partial, 4, 64);
        if (g == 0) ws_lds[k] = partial;
    }

    // ---- Phase 2: segment bounds (sorted ids -> contiguous range) ----
    if (wave == 0) {
        int v = wave_lower_bound(seg, N, b);
        if (lane == 0) se[0] = v;
    } else if (wave == 1) {
        int v = wave_lower_bound(seg, N, b + 1);
        if (lane == 0) se[1] = v;
    }
    __syncthreads();

    const int start = se[0];
    const int end   = se[1];
    const int last  = end - 1;
    const float4 wv = *reinterpret_cast<const float4*>(&ws_lds[4 * hl]);

    // ---- Phase 3: one-pass online softmax + weighted accumulation ----
    // Block covers 128 consecutive rows per iteration; wave w owns the 8 rows
    // [p+8w, p+8w+8); each 32-lane half owns 4 of them (interleaved pairs).
    // Loads are unconditional (row index clamped to `last`); invalid rows get
    // score SENT (finite) and weight e=0 — branch-free, pipelinable body.
    float  m = SENT, l = 0.f;
    float4 acc = make_float4(0.f, 0.f, 0.f, 0.f);

    for (int p = start; p < end; p += 128) {
        const int r0 = p + 8 * wave + half;
        const int r1 = r0 + 2, r2 = r0 + 4, r3 = r0 + 6;
        const int c0 = min(r0, last), c1 = min(r1, last);
        const int c2 = min(r2, last), c3 = min(r3, last);

        float4 x0 = *reinterpret_cast<const float4*>(x + (size_t)c0 * HDIM + 4 * hl);
        float4 x1 = *reinterpret_cast<const float4*>(x + (size_t)c1 * HDIM + 4 * hl);
        float4 x2 = *reinterpret_cast<const float4*>(x + (size_t)c2 * HDIM + 4 * hl);
        float4 x3 = *reinterpret_cast<const float4*>(x + (size_t)c3 * HDIM + 4 * hl);

        float h0 = x0.x * wv.x + x0.y * wv.y + x0.z * wv.z + x0.w * wv.w;
        float h1 = x1.x * wv.x + x1.y * wv.y + x1.z * wv.z + x1.w * wv.w;
        float h2 = x2.x * wv.x + x2.y * wv.y + x2.z * wv.z + x2.w * wv.w;
        float h3 = x3.x * wv.x + x3.y * wv.y + x3.z * wv.z + x3.w * wv.w;

        #pragma unroll
        for (int off = 16; off >= 1; off >>= 1) {   // reduce within 32-lane half
            h0 += __shfl_xor(h0, off, 64);
            h1 += __shfl_xor(h1, off, 64);
            h2 += __shfl_xor(h2, off, 64);
            h3 += __shfl_xor(h3, off, 64);
        }

        const bool v0 = r0 < end, v1 = r1 < end, v2 = r2 < end, v3 = r3 < end;
        h0 = v0 ? h0 : SENT;
        h1 = v1 ? h1 : SENT;
        h2 = v2 ? h2 : SENT;
        h3 = v3 ? h3 : SENT;

        float mn = fmaxf(fmaxf(fmaxf(fmaxf(m, h0), h1), h2), h3);
        float sc = __expf(m - mn);                  // m==SENT,mn==SENT -> 1, but l==0
        float e0 = v0 ? __expf(h0 - mn) : 0.f;
        float e1 = v1 ? __expf(h1 - mn) : 0.f;
        float e2 = v2 ? __expf(h2 - mn) : 0.f;
        float e3 = v3 ? __expf(h3 - mn) : 0.f;

        l = l * sc + ((e0 + e1) + (e2 + e3));
        acc.x = acc.x * sc + e0 * x0.x + e1 * x1.x + e2 * x2.x + e3 * x3.x;
        acc.y = acc.y * sc + e0 * x0.y + e1 * x1.y + e2 * x2.y + e3 * x3.y;
        acc.z = acc.z * sc + e0 * x0.z + e1 * x1.z + e2 * x2.z + e3 * x3.z;
        acc.w = acc.w * sc + e0 * x0.w + e1 * x1.w + e2 * x2.w + e3 * x3.w;
        m = mn;
    }

    // ---- Phase 4: merge the 32 half-wave online-softmax states ----
    const int st = wave * 2 + half;
    *reinterpret_cast<float4*>(&lacc[st][4 * hl]) = acc;
    if (hl == 0) { lm[st] = m; ll[st] = l; }
    __syncthreads();

    if (wave == 0 && lane < 32) {                   // parallel merge, xor<=16 stays in-half
        float mi = lm[lane], li = ll[lane];
        float M = mi;
        #pragma unroll
        for (int off = 16; off >= 1; off >>= 1) M = fmaxf(M, __shfl_xor(M, off, 64));
        float sc = (li > 0.f) ? __expf(mi - M) : 0.f;
        float d  = li * sc;
        #pragma unroll
        for (int off = 16; off >= 1; off >>= 1) d += __shfl_xor(d, off, 64);
        sscale[lane] = sc;
        if (lane == 0) sdenom = d;
    }
    __syncthreads();

    if (tid < HDIM) {
        float num = 0.f;
        #pragma unroll
        for (int i = 0; i < 32; ++i) num += lacc[i][tid] * sscale[i];
        float D = sdenom;
        out[(size_t)b * HDIM + tid] = (D > 0.f) ? (num / D) : 0.f;  // empty segment -> 0
    }
}

extern "C" void kernel_launch(void* const* d_in, const int* in_sizes, int n_in,
                              void* d_out, int out_size, void* d_ws, size_t ws_size,
                              hipStream_t stream) {
    const float* s   = (const float*)d_in[0];  // [B,H]
    const float* x   = (const float*)d_in[1];  // [N,H]
    const float* W   = (const float*)d_in[2];  // [H,H]
    const int*   seg = (const int*)  d_in[3];  // [N]
    float* out = (float*)d_out;

    const int B = in_sizes[0] / HDIM;
    const int N = in_sizes[3];

    att_pool_kernel<<<B, 1024, 0, stream>>>(s, x, W, seg, out, N, B);
}